// Round 12
// baseline (2510.107 us; speedup 1.0000x reference)
//
#include <hip/hip_runtime.h>

typedef unsigned short u16;
typedef unsigned int u32;
typedef __attribute__((ext_vector_type(8))) short short8;
typedef __attribute__((ext_vector_type(4))) short short4v;
typedef __attribute__((ext_vector_type(4))) float f32x4;

#define D_MODEL 512
#define NH 8
#define TSEQ 4096
#define NB 16
#define NROWS (NB*TSEQ)          // 65536 tokens per modality
#define M2 (2*NROWS)             // 131072 merged rows
#define QK_SCALE 0.125f          // DH^-0.5 / TEMP
#define KDIM 512
#define NKI (KDIM/32)            // 16 K-iterations of BK=32

__device__ __forceinline__ float b2f(u16 u){
    union { float f; unsigned int i; } v; v.i = ((unsigned int)u) << 16; return v.f;
}
__device__ __forceinline__ u16 f2b(float f){
    union { float f; unsigned int i; } v; v.f = f;
    unsigned int r = v.i + 0x7FFFu + ((v.i >> 16) & 1u);   // RNE
    return (u16)(r >> 16);
}

// async global->LDS, 16B/lane; LDS dest = wave-uniform base + lane*16
__device__ __forceinline__ void async_copy16(u16* lds, const u16* g){
    __builtin_amdgcn_global_load_lds(
        (const __attribute__((address_space(1))) u32*)g,
        (__attribute__((address_space(3))) u32*)lds, 16, 0, 0);
}

// ------- weight convert, ALL weights in one dispatch: W_i (512 x N_i fp32) -> dst (N_i x 512 bf16) ----
__global__ void wconv_all_kernel(
    const float* __restrict__ s0, const float* __restrict__ s1,
    const float* __restrict__ s2, const float* __restrict__ s3,
    const float* __restrict__ s4, const float* __restrict__ s5,
    const float* __restrict__ s6, u16* __restrict__ dst)
{
    int idx = blockIdx.x * 256 + threadIdx.x;     // < 3145728
    int off = idx;
    const float* W; int N;
    if      (off < 786432)                    { W = s0; N = 1536; }
    else if ((off -= 786432) < 262144)        { W = s1; N = 512;  }
    else if ((off -= 262144) < 786432)        { W = s2; N = 1536; }
    else if ((off -= 786432) < 262144)        { W = s3; N = 512;  }
    else if ((off -= 262144) < 262144)        { W = s4; N = 512;  }
    else if ((off -= 262144) < 524288)        { W = s5; N = 1024; }
    else    { off -= 524288;                    W = s6; N = 512;  }
    int n = off >> 9;
    int k = off & 511;
    dst[idx] = f2b(W[(size_t)k * N + n]);
}

// ---------------- LayerNorm: fp32 in -> bf16 out (one wave per row) ----------------
__global__ __launch_bounds__(256) void ln_kernel(
    const float* __restrict__ X, const float* __restrict__ g,
    const float* __restrict__ b, u16* __restrict__ out)
{
    int row  = blockIdx.x * 4 + (threadIdx.x >> 6);
    int lane = threadIdx.x & 63;
    size_t base = (size_t)row * D_MODEL + lane * 8;
    float4 x0 = *(const float4*)(X + base);
    float4 x1 = *(const float4*)(X + base + 4);
    float t[8] = {x0.x,x0.y,x0.z,x0.w,x1.x,x1.y,x1.z,x1.w};
    float s = 0.f, ss = 0.f;
    #pragma unroll
    for (int j = 0; j < 8; j++){ s += t[j]; ss += t[j]*t[j]; }
    #pragma unroll
    for (int m = 1; m < 64; m <<= 1){ s += __shfl_xor(s, m); ss += __shfl_xor(ss, m); }
    float mean = s * (1.f/D_MODEL);
    float var  = ss * (1.f/D_MODEL) - mean*mean;
    float rst  = rsqrtf(var + 1e-5f);
    float4 g0 = *(const float4*)(g + lane*8);
    float4 g1 = *(const float4*)(g + lane*8 + 4);
    float4 c0 = *(const float4*)(b + lane*8);
    float4 c1 = *(const float4*)(b + lane*8 + 4);
    float gv[8] = {g0.x,g0.y,g0.z,g0.w,g1.x,g1.y,g1.z,g1.w};
    float bv[8] = {c0.x,c0.y,c0.z,c0.w,c1.x,c1.y,c1.z,c1.w};
    short8 o;
    #pragma unroll
    for (int j = 0; j < 8; j++) o[j] = (short)f2b((t[j]-mean)*rst*gv[j] + bv[j]);
    *(short8*)(out + base) = o;
}

// ------- residual + LN, templated on Xin/out dtype (+opt bf16 Add, +opt next-LN) ----
template<int XINBF, int OUTBF>
__global__ __launch_bounds__(256) void resln_kernel(
    const u16* __restrict__ P, const void* __restrict__ Xin,
    const u16* __restrict__ Add,
    const float* __restrict__ g, const float* __restrict__ b,
    void* __restrict__ out,
    u16* __restrict__ lnout, const float* __restrict__ g2, const float* __restrict__ b2)
{
    int row  = blockIdx.x * 4 + (threadIdx.x >> 6);
    int lane = threadIdx.x & 63;
    size_t base = (size_t)row * D_MODEL + lane * 8;
    short8 pv = *(const short8*)(P + base);
    float t[8];
    if constexpr (XINBF){
        short8 xv = *(const short8*)((const u16*)Xin + base);
        #pragma unroll
        for (int j = 0; j < 8; j++) t[j] = b2f((u16)pv[j]) + b2f((u16)xv[j]);
    } else {
        float4 x0 = *(const float4*)((const float*)Xin + base);
        float4 x1 = *(const float4*)((const float*)Xin + base + 4);
        float xr[8] = {x0.x,x0.y,x0.z,x0.w,x1.x,x1.y,x1.z,x1.w};
        #pragma unroll
        for (int j = 0; j < 8; j++) t[j] = b2f((u16)pv[j]) + xr[j];
    }
    float s = 0.f, ss = 0.f;
    #pragma unroll
    for (int j = 0; j < 8; j++){ s += t[j]; ss += t[j]*t[j]; }
    #pragma unroll
    for (int m = 1; m < 64; m <<= 1){ s += __shfl_xor(s, m); ss += __shfl_xor(ss, m); }
    float mean = s * (1.f/D_MODEL);
    float var  = ss * (1.f/D_MODEL) - mean*mean;
    float rst  = rsqrtf(var + 1e-5f);
    float4 g0 = *(const float4*)(g + lane*8);
    float4 g1 = *(const float4*)(g + lane*8 + 4);
    float4 c0 = *(const float4*)(b + lane*8);
    float4 c1 = *(const float4*)(b + lane*8 + 4);
    float gv[8] = {g0.x,g0.y,g0.z,g0.w,g1.x,g1.y,g1.z,g1.w};
    float bv[8] = {c0.x,c0.y,c0.z,c0.w,c1.x,c1.y,c1.z,c1.w};
    float o[8];
    #pragma unroll
    for (int j = 0; j < 8; j++) o[j] = (t[j]-mean)*rst*gv[j] + bv[j];

    if (lnout){
        float s2 = 0.f, ss2 = 0.f;
        #pragma unroll
        for (int j = 0; j < 8; j++){ s2 += o[j]; ss2 += o[j]*o[j]; }
        #pragma unroll
        for (int m = 1; m < 64; m <<= 1){ s2 += __shfl_xor(s2, m); ss2 += __shfl_xor(ss2, m); }
        float mean2 = s2 * (1.f/D_MODEL);
        float var2  = ss2 * (1.f/D_MODEL) - mean2*mean2;
        float rst2  = rsqrtf(var2 + 1e-5f);
        float4 g20 = *(const float4*)(g2 + lane*8);
        float4 g21 = *(const float4*)(g2 + lane*8 + 4);
        float4 b20 = *(const float4*)(b2 + lane*8);
        float4 b21 = *(const float4*)(b2 + lane*8 + 4);
        float g2v[8] = {g20.x,g20.y,g20.z,g20.w,g21.x,g21.y,g21.z,g21.w};
        float b2v[8] = {b20.x,b20.y,b20.z,b20.w,b21.x,b21.y,b21.z,b21.w};
        short8 lo;
        #pragma unroll
        for (int j = 0; j < 8; j++) lo[j] = (short)f2b((o[j]-mean2)*rst2*g2v[j] + b2v[j]);
        *(short8*)(lnout + base) = lo;
    }
    if (Add){
        short8 av = *(const short8*)(Add + base);
        #pragma unroll
        for (int j = 0; j < 8; j++) o[j] += b2f((u16)av[j]);
    }
    if constexpr (OUTBF){
        short8 ov;
        #pragma unroll
        for (int j = 0; j < 8; j++) ov[j] = (short)f2b(o[j]);
        *(short8*)((u16*)out + base) = ov;
    } else {
        float4 r0 = {o[0],o[1],o[2],o[3]};
        float4 r1 = {o[4],o[5],o[6],o[7]};
        *(float4*)((float*)out + base)     = r0;
        *(float4*)((float*)out + base + 4) = r1;
    }
}

// ======== fused QKV-GEMM + window attention (WIN=2), merged 2-modality, one head/block ====
// grid 8192: XCD owns one head; rt in [0,1024) spans x-half (rt<512) then y-half.
__global__ __launch_bounds__(256) void qkvattn_kernel(
    const u16* __restrict__ A, const u16* __restrict__ Wt0, const u16* __restrict__ Wt1,
    const float* __restrict__ bias0, const float* __restrict__ bias1,
    u16* __restrict__ O, int shift)
{
    __shared__ __align__(16) u16 lds[2][20*512];   // chunks: 0-7 A(128x32), 8-19 B(192x32)
    int tid  = threadIdx.x;
    int lane = tid & 63;
    int wid  = tid >> 6;

    int bid  = blockIdx.x;
    int swz  = (bid & 7) * 1024 + (bid >> 3);
    int head = swz >> 10;          // 0..7 (== XCD)
    int rt   = swz & 1023;         // 0..1023
    int half = rt >> 9;
    int hrt  = rt & 511;
    int bt   = hrt >> 5;           // batch within half
    int tb   = (hrt & 31) * 128;   // token base within batch

    const u16*  Wt   = half ? Wt1   : Wt0;
    const float* bias = half ? bias1 : bias0;
    const u16* Ab = A + (size_t)half * NROWS * D_MODEL;
    u16*       Ob = O + (size_t)half * NROWS * D_MODEL;

    f32x4 acc[2][12];
    f32x4 zero = {0.f,0.f,0.f,0.f};
    #pragma unroll
    for (int m = 0; m < 2; m++)
        #pragma unroll
        for (int n = 0; n < 12; n++) acc[m][n] = zero;

    int rr = lane >> 2, kc = (lane & 3) * 8;
    const u16* p[5];
    int cidb = wid * 5;
    #pragma unroll
    for (int q = 0; q < 5; q++){
        int cid = cidb + q;
        if (cid < 8){
            int i   = cid*16 + rr;
            int tok = (tb + shift + i) & (TSEQ-1);
            p[q] = Ab + ((size_t)bt * TSEQ + tok) * KDIM + kc;
        } else {
            int cb   = cid - 8;
            int wrow = (cb >> 2) * 512 + head*64 + (cb & 3)*16 + rr;
            p[q] = Wt + (size_t)wrow * KDIM + kc;
        }
    }

    int lrow = lane & 15;
    int lk   = (lane >> 4) * 8;
    int aoff = (wid*32 + lrow) * 32 + lk;       // + m*16*32
    int boff = 8*512 + lrow*32 + lk;            // + n*16*32

    #pragma unroll
    for (int q = 0; q < 5; q++){ async_copy16(&lds[0][(cidb+q)*512], p[q]); p[q] += 32; }
    asm volatile("s_waitcnt vmcnt(0)" ::: "memory");
    __syncthreads();

    #pragma unroll
    for (int t = 0; t < NKI; t++){
        const u16* cbuf = lds[t & 1];
        u16* nbuf = (u16*)lds[(t & 1) ^ 1];
        if (t < NKI-1){
            #pragma unroll
            for (int q = 0; q < 5; q++){ async_copy16(&nbuf[(cidb+q)*512], p[q]); p[q] += 32; }
        }
        short8 af[2], bf[12];
        #pragma unroll
        for (int m = 0; m < 2; m++) af[m] = *(const short8*)(cbuf + aoff + m*512);
        #pragma unroll
        for (int n = 0; n < 12; n++) bf[n] = *(const short8*)(cbuf + boff + n*512);
        #pragma unroll
        for (int m = 0; m < 2; m++)
            #pragma unroll
            for (int n = 0; n < 12; n++)
                acc[m][n] = __builtin_amdgcn_mfma_f32_16x16x32_bf16(af[m], bf[n], acc[m][n], 0, 0, 0);
        if (t < NKI-1){
            asm volatile("s_waitcnt vmcnt(0)" ::: "memory");
            __syncthreads();
        }
    }

    // ---- attention epilogue ----
    int g_ = lane >> 4, lc = lane & 15;
    float bq[4], bk[4], bv[4];
    #pragma unroll
    for (int n = 0; n < 4; n++){
        int d = head*64 + n*16 + lc;
        bq[n] = bias[d]; bk[n] = bias[512 + d]; bv[n] = bias[1024 + d];
    }
    #pragma unroll
    for (int m = 0; m < 2; m++){
        #pragma unroll
        for (int wnd = 0; wnd < 2; wnd++){
            int ja = 2*wnd, jb = ja + 1;
            float s00=0.f, s01=0.f, s10=0.f, s11=0.f;
            #pragma unroll
            for (int n = 0; n < 4; n++){
                float qa = acc[m][n][ja] + bq[n],  qb = acc[m][n][jb] + bq[n];
                float ka = acc[m][4+n][ja] + bk[n], kb = acc[m][4+n][jb] + bk[n];
                s00 += qa*ka; s01 += qa*kb; s10 += qb*ka; s11 += qb*kb;
            }
            #pragma unroll
            for (int msk = 1; msk < 16; msk <<= 1){
                s00 += __shfl_xor(s00, msk); s01 += __shfl_xor(s01, msk);
                s10 += __shfl_xor(s10, msk); s11 += __shfl_xor(s11, msk);
            }
            s00 *= QK_SCALE; s01 *= QK_SCALE; s10 *= QK_SCALE; s11 *= QK_SCALE;
            float m0 = fmaxf(s00, s01), m1 = fmaxf(s10, s11);
            float e00 = expf(s00-m0), e01 = expf(s01-m0);
            float e10 = expf(s10-m1), e11 = expf(s11-m1);
            float ia = 1.f/(e00+e01), ib = 1.f/(e10+e11);
            float a00 = e00*ia, a01 = e01*ia, a10 = e10*ib, a11 = e11*ib;
            int ra = wid*32 + m*16 + 4*g_ + ja;
            int ta = (tb + shift + ra) & (TSEQ-1);
            size_t growa = (size_t)bt * TSEQ + ta;
            size_t growb = (size_t)bt * TSEQ + ((ta + 1) & (TSEQ-1));
            #pragma unroll
            for (int n = 0; n < 4; n++){
                float va = acc[m][8+n][ja] + bv[n], vb = acc[m][8+n][jb] + bv[n];
                int col = head*64 + n*16 + lc;
                Ob[growa * D_MODEL + col] = f2b(a00*va + a01*vb);
                Ob[growb * D_MODEL + col] = f2b(a10*va + a11*vb);
            }
        }
    }
}

// ======== gemm256: m201-style 8-phase schedule, 256x256 tile, BK=64 ========
// Per-half weights: rows >= halfM use Wt1/bias1 (pass Wt0==Wt1 for shared).
#define AOFc(buf,h) (((buf)*2+(h))*8192)
#define BOFc(buf,h) (32768 + ((buf)*2+(h))*8192)

__global__ __launch_bounds__(512, 2) void gemm256_kernel(
    const u16* __restrict__ A,
    const u16* __restrict__ Wt0, const u16* __restrict__ Wt1,
    const float* __restrict__ bias0, const float* __restrict__ bias1,
    u16* __restrict__ C, int N, int nN, int halfM)
{
    __shared__ __align__(16) u16 sh[65536];   // 128 KiB
    u16* sh_ = (u16*)sh;
    const int tid = threadIdx.x, lane = tid & 63, wid = tid >> 6;
    const int wm = wid >> 2, wn = wid & 3;
    const int cpx = (int)gridDim.x >> 3;
    const int swz = ((int)blockIdx.x & 7) * cpx + ((int)blockIdx.x >> 3);
    const int row0 = (swz / nN) * 256;
    const int col0 = (swz % nN) * 256;

    const u16*  Wt   = (row0 >= halfM) ? Wt1   : Wt0;
    const float* bias = (row0 >= halfM) ? bias1 : bias0;

    f32x4 acc[8][4];
    f32x4 zero = {0.f,0.f,0.f,0.f};
    #pragma unroll
    for (int m = 0; m < 8; m++)
        #pragma unroll
        for (int n = 0; n < 4; n++) acc[m][n] = zero;

    const int lrow = lane & 15, khi = lane >> 4;
    const int swx   = (lrow & 4) << 2;
    const int kcol0 = (khi*8) ^ swx;
    const int kcol1 = (32 + khi*8) ^ swx;
    const int aR0 = AOFc(0, wm) , aR1 = AOFc(1, wm);
    const int bh  = wn >> 1;
    const int bR0 = BOFc(0, bh), bR1 = BOFc(1, bh);
    const int abase = lrow*64;
    const int bbase = (wn & 1)*4096 + lrow*64;

    const u16* Ag = A  + (size_t)row0 * KDIM;
    const u16* Bg = Wt + (size_t)col0 * KDIM;
    const int csrc = ((lane & 7) * 8) ^ (((lane >> 3) & 4) << 2);
    const int srow = wid*16 + (lane >> 3);

    short8 af[4][2], bf[4][2];

    #define STG(dstOff, gp) { \
        const u16* s1_ = (gp) + (size_t)srow*KDIM + csrc; \
        u16* d1_ = sh_ + (dstOff) + wid*1024; \
        async_copy16(d1_, s1_); \
        async_copy16(d1_ + 512, s1_ + (size_t)8*KDIM); }
    #define RDA(bufR, h) { \
        const u16* p_ = sh_ + (bufR) + abase; \
        _Pragma("unroll") \
        for (int i_ = 0; i_ < 4; i_++){ \
            af[i_][0] = *(const short8*)(p_ + ((h)*4+i_)*1024 + kcol0); \
            af[i_][1] = *(const short8*)(p_ + ((h)*4+i_)*1024 + kcol1); } }
    #define RDB(bufR, nh) { \
        const u16* p_ = sh_ + (bufR) + bbase; \
        _Pragma("unroll") \
        for (int j_ = 0; j_ < 2; j_++){ \
            bf[(nh)*2+j_][0] = *(const short8*)(p_ + ((nh)*2+j_)*1024 + kcol0); \
            bf[(nh)*2+j_][1] = *(const short8*)(p_ + ((nh)*2+j_)*1024 + kcol1); } }
    #define MM(mh, nh) { \
        __builtin_amdgcn_s_setprio(1); \
        _Pragma("unroll") \
        for (int m_ = 0; m_ < 4; m_++) \
            _Pragma("unroll") \
            for (int n_ = 0; n_ < 2; n_++){ \
                acc[(mh)*4+m_][(nh)*2+n_] = __builtin_amdgcn_mfma_f32_16x16x32_bf16(af[m_][0], bf[(nh)*2+n_][0], acc[(mh)*4+m_][(nh)*2+n_], 0,0,0); \
                acc[(mh)*4+m_][(nh)*2+n_] = __builtin_amdgcn_mfma_f32_16x16x32_bf16(af[m_][1], bf[(nh)*2+n_][1], acc[(mh)*4+m_][(nh)*2+n_], 0,0,0); } \
        __builtin_amdgcn_s_setprio(0); }
    #define BAR() { asm volatile("" ::: "memory"); __builtin_amdgcn_s_barrier(); asm volatile("" ::: "memory"); }
    #define VMW4() asm volatile("s_waitcnt vmcnt(4)" ::: "memory")
    #define VMW0() asm volatile("s_waitcnt vmcnt(0)" ::: "memory")

    STG(BOFc(0,0), Bg);
    STG(BOFc(0,1), Bg + (size_t)128*KDIM);
    STG(AOFc(0,0), Ag);
    STG(AOFc(0,1), Ag + (size_t)128*KDIM);
    STG(BOFc(1,0), Bg + 64);
    STG(BOFc(1,1), Bg + (size_t)128*KDIM + 64);
    VMW4();
    BAR();

    #pragma unroll
    for (int i = 0; i < 4; i++){
        RDA(aR0, 0); RDB(bR0, 0);
        STG(AOFc(1,0), Ag + (2*i+1)*64);
        BAR(); MM(0,0); BAR();

        RDB(bR0, 1);
        STG(AOFc(1,1), Ag + (size_t)128*KDIM + (2*i+1)*64);
        BAR(); MM(0,1); BAR();

        RDA(aR0, 1);
        if (i < 3) STG(BOFc(0,0), Bg + (2*i+2)*64);
        BAR(); MM(1,0); BAR();

        if (i < 3){ STG(BOFc(0,1), Bg + (size_t)128*KDIM + (2*i+2)*64); VMW4(); }
        else      { VMW0(); }
        BAR(); MM(1,1); BAR();

        RDA(aR1, 0); RDB(bR1, 0);
        if (i < 3) STG(AOFc(0,0), Ag + (2*i+2)*64);
        BAR(); MM(0,0); BAR();

        RDB(bR1, 1);
        if (i < 3) STG(AOFc(0,1), Ag + (size_t)128*KDIM + (2*i+2)*64);
        BAR(); MM(0,1); BAR();

        RDA(aR1, 1);
        if (i < 3) STG(BOFc(1,0), Bg + (2*i+3)*64);
        BAR(); MM(1,0); BAR();

        if (i < 3){ STG(BOFc(1,1), Bg + (size_t)128*KDIM + (2*i+3)*64); VMW4(); }
        BAR(); MM(1,1); BAR();
    }

    int g_ = lane >> 4, lc = lane & 15;
    #pragma unroll
    for (int n = 0; n < 4; n++){
        int c = col0 + wn*64 + n*16 + lc;
        float bvv = bias[c];
        #pragma unroll
        for (int m = 0; m < 8; m++){
            int r = row0 + wm*128 + m*16 + 4*g_;
            f32x4 v = acc[m][n];
            C[(size_t)(r+0) * N + c] = f2b(v[0] + bvv);
            C[(size_t)(r+1) * N + c] = f2b(v[1] + bvv);
            C[(size_t)(r+2) * N + c] = f2b(v[2] + bvv);
            C[(size_t)(r+3) * N + c] = f2b(v[3] + bvv);
        }
    }
    #undef STG
    #undef RDA
    #undef RDB
    #undef MM
    #undef BAR
    #undef VMW4
    #undef VMW0
}

// ---- cross-attn merged: Q rows [0,2M); KV partner row = row ^ NROWS (other modality) ----
__global__ __launch_bounds__(256) void attn_cross_kernel(
    const u16* __restrict__ Q, const u16* __restrict__ KV,
    u16* __restrict__ O, int shift)
{
    int tsk  = blockIdx.x * 4 + (threadIdx.x >> 6);   // window*2 + half
    int lane = threadIdx.x & 63;
    int w  = tsk >> 1;             // 0..65535 (32 batches x 2048 windows)
    int hb = tsk & 1;
    int bt = w >> 11;              // 0..31
    int wt = w & 2047;
    int t0 = (2*wt + shift) & (TSEQ - 1);
    int t1 = (t0 + 1) & (TSEQ - 1);
    size_t g0 = (size_t)bt * TSEQ + t0;
    size_t g1 = (size_t)bt * TSEQ + t1;
    size_t kg0 = g0 ^ (size_t)NROWS;   // partner modality
    size_t kg1 = g1 ^ (size_t)NROWS;
    int col = hb*256 + lane*4;
    short4v q0 = *(const short4v*)(Q  + g0*512  + col);
    short4v q1 = *(const short4v*)(Q  + g1*512  + col);
    short4v k0 = *(const short4v*)(KV + kg0*1024 + col);
    short4v k1 = *(const short4v*)(KV + kg1*1024 + col);
    short4v v0 = *(const short4v*)(KV + kg0*1024 + 512 + col);
    short4v v1 = *(const short4v*)(KV + kg1*1024 + 512 + col);
    float s00=0.f, s01=0.f, s10=0.f, s11=0.f;
    float v0f[4], v1f[4];
    #pragma unroll
    for (int j = 0; j < 4; j++){
        float qa = b2f((u16)q0[j]), qb = b2f((u16)q1[j]);
        float ka = b2f((u16)k0[j]), kb = b2f((u16)k1[j]);
        v0f[j] = b2f((u16)v0[j]); v1f[j] = b2f((u16)v1[j]);
        s00 += qa*ka; s01 += qa*kb; s10 += qb*ka; s11 += qb*kb;
    }
    #pragma unroll
    for (int m = 1; m < 16; m <<= 1){
        s00 += __shfl_xor(s00, m); s01 += __shfl_xor(s01, m);
        s10 += __shfl_xor(s10, m); s11 += __shfl_xor(s11, m);
    }
    s00 *= QK_SCALE; s01 *= QK_SCALE; s10 *= QK_SCALE; s11 *= QK_SCALE;
    float m0 = fmaxf(s00, s01), m1 = fmaxf(s10, s11);
    float e00 = expf(s00 - m0), e01 = expf(s01 - m0);
    float e10 = expf(s10 - m1), e11 = expf(s11 - m1);
    float ia = 1.f/(e00 + e01), ib = 1.f/(e10 + e11);
    float a00 = e00*ia, a01 = e01*ia, a10 = e10*ib, a11 = e11*ib;
    short4v o0, o1;
    #pragma unroll
    for (int j = 0; j < 4; j++){
        o0[j] = (short)f2b(a00*v0f[j] + a01*v1f[j]);
        o1[j] = (short)f2b(a10*v0f[j] + a11*v1f[j]);
    }
    *(short4v*)(O + g0*512 + col) = o0;
    *(short4v*)(O + g1*512 + col) = o1;
}

// ============================== host side ==============================
extern "C" void kernel_launch(void* const* d_in, const int* in_sizes, int n_in,
                              void* d_out, int out_size, void* d_ws, size_t ws_size,
                              hipStream_t stream)
{
    const float* x = (const float*)d_in[0];
    const float* y = (const float*)d_in[1];
    const float* wa_qkv_w = (const float*)d_in[2];  const float* wa_qkv_b = (const float*)d_in[3];
    const float* wa_proj_w= (const float*)d_in[4];  const float* wa_proj_b= (const float*)d_in[5];
    const float* wa_n1g   = (const float*)d_in[6];  const float* wa_n1b   = (const float*)d_in[7];
    const float* wa_n2g   = (const float*)d_in[8];  const float* wa_n2b   = (const float*)d_in[9];
    const float* wv_qkv_w = (const float*)d_in[10]; const float* wv_qkv_b = (const float*)d_in[11];
    const float* wv_proj_w= (const float*)d_in[12]; const float* wv_proj_b= (const float*)d_in[13];
    const float* wv_n1g   = (const float*)d_in[14]; const float* wv_n1b   = (const float*)d_in[15];
    const float* wv_n2g   = (const float*)d_in[16]; const float* wv_n2b   = (const float*)d_in[17];
    const float* cm_q_w   = (const float*)d_in[18]; const float* cm_q_b   = (const float*)d_in[19];
    const float* cm_kv_w  = (const float*)d_in[20]; const float* cm_kv_b  = (const float*)d_in[21];
    const float* cm_proj_w= (const float*)d_in[22]; const float* cm_proj_b= (const float*)d_in[23];
    const float* cm_n1g   = (const float*)d_in[24]; const float* cm_n1b   = (const float*)d_in[25];
    const float* cm_n2g   = (const float*)d_in[26]; const float* cm_n2b   = (const float*)d_in[27];

    char* ws = (char*)d_ws;
    const size_t HALF = (size_t)NROWS * D_MODEL;         // elements per half
    const size_t SZ2  = (size_t)M2 * D_MODEL * 2;        // 134 MB (2M bf16)
    u16* F1b = (u16*)(ws);                    // residual stream (2M)
    u16* SFb = (u16*)(ws + 1*SZ2);            // self outputs [x;y]
    u16* SLN = (u16*)(ws + 2*SZ2);            // LN(cm_n1) of self outputs; CN aliases
    u16* XN  = (u16*)(ws + 3*SZ2);            // ln-out / Qall / P
    u16* O   = (u16*)(ws + 4*SZ2);            // attn outputs
    u16* KVA = (u16*)(ws + 5*SZ2);            // 2M x 1024 (cross); PB aliases (self)
    u16* WB  = (u16*)(ws + 7*SZ2);

    u16* CN = SLN;                 // alias: SLN dead after q-gemm #1
    u16* PB = KVA;                 // proj-output scratch during self phase

    u16* wa_qkv_t  = WB;
    u16* wa_proj_t = wa_qkv_t  + 1536*512;
    u16* wv_qkv_t  = wa_proj_t + 512*512;
    u16* wv_proj_t = wv_qkv_t  + 1536*512;
    u16* cm_q_t    = wv_proj_t + 512*512;
    u16* cm_kv_t   = cm_q_t    + 512*512;
    u16* cm_proj_t = cm_kv_t   + 1024*512;

    // all 7 weight transposes in one dispatch (3145728 elems)
    wconv_all_kernel<<<12288, 256, 0, stream>>>(
        wa_qkv_w, wa_proj_w, wv_qkv_w, wv_proj_w, cm_q_w, cm_kv_w, cm_proj_w, wa_qkv_t);

    const int lnGridH   = NROWS / 4;          // per-half ln/resln grid
    const int rlGrid2   = M2 / 4;             // merged resln grid
    const int attnGrid2 = M2 / 2 * 2 / 4;     // 32768
    const int qaGrid2   = (M2 / 128) * NH;    // 8192 (head x 1024 row-tiles)

    auto gemm = [&](const u16* Ain, const u16* W0, const u16* W1,
                    const float* b0, const float* b1, u16* Cout, int N, int halfM){
        int nN = N / 256;
        gemm256_kernel<<<(M2/256) * nN, 512, 0, stream>>>(Ain, W0, W1, b0, b1, Cout, N, nN, halfM);
    };

    // ================= self phase (x and y merged; per-half weights) =================
    ln_kernel<<<lnGridH, 256, 0, stream>>>(x, wa_n1g, wa_n1b, XN);
    ln_kernel<<<lnGridH, 256, 0, stream>>>(y, wv_n1g, wv_n1b, XN + HALF);

    qkvattn_kernel<<<qaGrid2, 256, 0, stream>>>(XN, wa_qkv_t, wv_qkv_t, wa_qkv_b, wv_qkv_b, O, 0);
    gemm(O, wa_proj_t, wv_proj_t, wa_proj_b, wv_proj_b, PB, 512, NROWS);
    resln_kernel<0,1><<<lnGridH, 256, 0, stream>>>(PB,        x, nullptr, wa_n2g, wa_n2b, F1b,        XN,        wa_n1g, wa_n1b);
    resln_kernel<0,1><<<lnGridH, 256, 0, stream>>>(PB + HALF, y, nullptr, wv_n2g, wv_n2b, F1b + HALF, XN + HALF, wv_n1g, wv_n1b);

    qkvattn_kernel<<<qaGrid2, 256, 0, stream>>>(XN, wa_qkv_t, wv_qkv_t, wa_qkv_b, wv_qkv_b, O, 1);
    gemm(O, wa_proj_t, wv_proj_t, wa_proj_b, wv_proj_b, PB, 512, NROWS);
    resln_kernel<1,1><<<lnGridH, 256, 0, stream>>>(PB,        F1b,        nullptr, wa_n2g, wa_n2b, SFb,        SLN,        cm_n1g, cm_n1b);
    resln_kernel<1,1><<<lnGridH, 256, 0, stream>>>(PB + HALF, F1b + HALF, nullptr, wv_n2g, wv_n2b, SFb + HALF, SLN + HALF, cm_n1g, cm_n1b);

    // ================= cross phase (fully merged; shared cm weights) =================
    float* outF = (float*)d_out;   // 2M rows fp32, [x-result; y-result] contiguous

    gemm(SLN, cm_kv_t, cm_kv_t, cm_kv_b, cm_kv_b, KVA, 1024, M2);       // KV once, both modalities
    gemm(SLN, cm_q_t,  cm_q_t,  cm_q_b,  cm_q_b,  XN,  512,  M2);       // Q all
    attn_cross_kernel<<<attnGrid2, 256, 0, stream>>>(XN, KVA, O, 0);
    gemm(O, cm_proj_t, cm_proj_t, cm_proj_b, cm_proj_b, XN, 512, M2);
    resln_kernel<1,1><<<rlGrid2, 256, 0, stream>>>(XN, SFb, nullptr, cm_n2g, cm_n2b, F1b, CN, cm_n1g, cm_n1b);

    gemm(CN, cm_q_t, cm_q_t, cm_q_b, cm_q_b, XN, 512, M2);
    attn_cross_kernel<<<attnGrid2, 256, 0, stream>>>(XN, KVA, O, 1);
    gemm(O, cm_proj_t, cm_proj_t, cm_proj_b, cm_proj_b, XN, 512, M2);
    resln_kernel<1,0><<<rlGrid2, 256, 0, stream>>>(XN, F1b, SFb, cm_n2g, cm_n2b, outF, nullptr, nullptr, nullptr);
}

// Round 13
// 2211.291 us; speedup vs baseline: 1.1351x; 1.1351x over previous
//
#include <hip/hip_runtime.h>

typedef unsigned short u16;
typedef unsigned int u32;
typedef __attribute__((ext_vector_type(8))) short short8;
typedef __attribute__((ext_vector_type(4))) short short4v;
typedef __attribute__((ext_vector_type(4))) float f32x4;

#define D_MODEL 512
#define NH 8
#define TSEQ 4096
#define NB 16
#define NROWS (NB*TSEQ)          // 65536 tokens per modality
#define M2 (2*NROWS)             // 131072 merged rows
#define QK_SCALE 0.125f          // DH^-0.5 / TEMP
#define KDIM 512
#define NKI (KDIM/32)            // 16 K-iterations of BK=32

__device__ __forceinline__ float b2f(u16 u){
    union { float f; unsigned int i; } v; v.i = ((unsigned int)u) << 16; return v.f;
}
__device__ __forceinline__ u16 f2b(float f){
    union { float f; unsigned int i; } v; v.f = f;
    unsigned int r = v.i + 0x7FFFu + ((v.i >> 16) & 1u);   // RNE
    return (u16)(r >> 16);
}

// async global->LDS, 16B/lane; LDS dest = wave-uniform base + lane*16
__device__ __forceinline__ void async_copy16(u16* lds, const u16* g){
    __builtin_amdgcn_global_load_lds(
        (const __attribute__((address_space(1))) u32*)g,
        (__attribute__((address_space(3))) u32*)lds, 16, 0, 0);
}

// ------- weight convert, ALL weights in one dispatch: W_i (512 x N_i fp32) -> dst (N_i x 512 bf16) ----
__global__ void wconv_all_kernel(
    const float* __restrict__ s0, const float* __restrict__ s1,
    const float* __restrict__ s2, const float* __restrict__ s3,
    const float* __restrict__ s4, const float* __restrict__ s5,
    const float* __restrict__ s6, u16* __restrict__ dst)
{
    int idx = blockIdx.x * 256 + threadIdx.x;     // < 3145728
    int off = idx;
    const float* W; int N;
    if      (off < 786432)                    { W = s0; N = 1536; }
    else if ((off -= 786432) < 262144)        { W = s1; N = 512;  }
    else if ((off -= 262144) < 786432)        { W = s2; N = 1536; }
    else if ((off -= 786432) < 262144)        { W = s3; N = 512;  }
    else if ((off -= 262144) < 262144)        { W = s4; N = 512;  }
    else if ((off -= 262144) < 524288)        { W = s5; N = 1024; }
    else    { off -= 524288;                    W = s6; N = 512;  }
    int n = off >> 9;
    int k = off & 511;
    dst[idx] = f2b(W[(size_t)k * N + n]);
}

// ---------------- LayerNorm: fp32 in -> bf16 out (one wave per row) ----------------
__global__ __launch_bounds__(256) void ln_kernel(
    const float* __restrict__ X, const float* __restrict__ g,
    const float* __restrict__ b, u16* __restrict__ out)
{
    int row  = blockIdx.x * 4 + (threadIdx.x >> 6);
    int lane = threadIdx.x & 63;
    size_t base = (size_t)row * D_MODEL + lane * 8;
    float4 x0 = *(const float4*)(X + base);
    float4 x1 = *(const float4*)(X + base + 4);
    float t[8] = {x0.x,x0.y,x0.z,x0.w,x1.x,x1.y,x1.z,x1.w};
    float s = 0.f, ss = 0.f;
    #pragma unroll
    for (int j = 0; j < 8; j++){ s += t[j]; ss += t[j]*t[j]; }
    #pragma unroll
    for (int m = 1; m < 64; m <<= 1){ s += __shfl_xor(s, m); ss += __shfl_xor(ss, m); }
    float mean = s * (1.f/D_MODEL);
    float var  = ss * (1.f/D_MODEL) - mean*mean;
    float rst  = rsqrtf(var + 1e-5f);
    float4 g0 = *(const float4*)(g + lane*8);
    float4 g1 = *(const float4*)(g + lane*8 + 4);
    float4 c0 = *(const float4*)(b + lane*8);
    float4 c1 = *(const float4*)(b + lane*8 + 4);
    float gv[8] = {g0.x,g0.y,g0.z,g0.w,g1.x,g1.y,g1.z,g1.w};
    float bv[8] = {c0.x,c0.y,c0.z,c0.w,c1.x,c1.y,c1.z,c1.w};
    short8 o;
    #pragma unroll
    for (int j = 0; j < 8; j++) o[j] = (short)f2b((t[j]-mean)*rst*gv[j] + bv[j]);
    *(short8*)(out + base) = o;
}

// ------- residual + LN, templated on Xin/out dtype (+opt bf16 Add, +opt next-LN) ----
template<int XINBF, int OUTBF>
__global__ __launch_bounds__(256) void resln_kernel(
    const u16* __restrict__ P, const void* __restrict__ Xin,
    const u16* __restrict__ Add,
    const float* __restrict__ g, const float* __restrict__ b,
    void* __restrict__ out,
    u16* __restrict__ lnout, const float* __restrict__ g2, const float* __restrict__ b2)
{
    int row  = blockIdx.x * 4 + (threadIdx.x >> 6);
    int lane = threadIdx.x & 63;
    size_t base = (size_t)row * D_MODEL + lane * 8;
    short8 pv = *(const short8*)(P + base);
    float t[8];
    if constexpr (XINBF){
        short8 xv = *(const short8*)((const u16*)Xin + base);
        #pragma unroll
        for (int j = 0; j < 8; j++) t[j] = b2f((u16)pv[j]) + b2f((u16)xv[j]);
    } else {
        float4 x0 = *(const float4*)((const float*)Xin + base);
        float4 x1 = *(const float4*)((const float*)Xin + base + 4);
        float xr[8] = {x0.x,x0.y,x0.z,x0.w,x1.x,x1.y,x1.z,x1.w};
        #pragma unroll
        for (int j = 0; j < 8; j++) t[j] = b2f((u16)pv[j]) + xr[j];
    }
    float s = 0.f, ss = 0.f;
    #pragma unroll
    for (int j = 0; j < 8; j++){ s += t[j]; ss += t[j]*t[j]; }
    #pragma unroll
    for (int m = 1; m < 64; m <<= 1){ s += __shfl_xor(s, m); ss += __shfl_xor(ss, m); }
    float mean = s * (1.f/D_MODEL);
    float var  = ss * (1.f/D_MODEL) - mean*mean;
    float rst  = rsqrtf(var + 1e-5f);
    float4 g0 = *(const float4*)(g + lane*8);
    float4 g1 = *(const float4*)(g + lane*8 + 4);
    float4 c0 = *(const float4*)(b + lane*8);
    float4 c1 = *(const float4*)(b + lane*8 + 4);
    float gv[8] = {g0.x,g0.y,g0.z,g0.w,g1.x,g1.y,g1.z,g1.w};
    float bv[8] = {c0.x,c0.y,c0.z,c0.w,c1.x,c1.y,c1.z,c1.w};
    float o[8];
    #pragma unroll
    for (int j = 0; j < 8; j++) o[j] = (t[j]-mean)*rst*gv[j] + bv[j];

    if (lnout){
        float s2 = 0.f, ss2 = 0.f;
        #pragma unroll
        for (int j = 0; j < 8; j++){ s2 += o[j]; ss2 += o[j]*o[j]; }
        #pragma unroll
        for (int m = 1; m < 64; m <<= 1){ s2 += __shfl_xor(s2, m); ss2 += __shfl_xor(ss2, m); }
        float mean2 = s2 * (1.f/D_MODEL);
        float var2  = ss2 * (1.f/D_MODEL) - mean2*mean2;
        float rst2  = rsqrtf(var2 + 1e-5f);
        float4 g20 = *(const float4*)(g2 + lane*8);
        float4 g21 = *(const float4*)(g2 + lane*8 + 4);
        float4 b20 = *(const float4*)(b2 + lane*8);
        float4 b21 = *(const float4*)(b2 + lane*8 + 4);
        float g2v[8] = {g20.x,g20.y,g20.z,g20.w,g21.x,g21.y,g21.z,g21.w};
        float b2v[8] = {b20.x,b20.y,b20.z,b20.w,b21.x,b21.y,b21.z,b21.w};
        short8 lo;
        #pragma unroll
        for (int j = 0; j < 8; j++) lo[j] = (short)f2b((o[j]-mean2)*rst2*g2v[j] + b2v[j]);
        *(short8*)(lnout + base) = lo;
    }
    if (Add){
        short8 av = *(const short8*)(Add + base);
        #pragma unroll
        for (int j = 0; j < 8; j++) o[j] += b2f((u16)av[j]);
    }
    if constexpr (OUTBF){
        short8 ov;
        #pragma unroll
        for (int j = 0; j < 8; j++) ov[j] = (short)f2b(o[j]);
        *(short8*)((u16*)out + base) = ov;
    } else {
        float4 r0 = {o[0],o[1],o[2],o[3]};
        float4 r1 = {o[4],o[5],o[6],o[7]};
        *(float4*)((float*)out + base)     = r0;
        *(float4*)((float*)out + base + 4) = r1;
    }
}

// ======== fused QKV-GEMM + window attention (WIN=2), single modality (R10-proven) ========
__global__ __launch_bounds__(256) void qkvattn_kernel(
    const u16* __restrict__ A, const u16* __restrict__ Wt,
    const float* __restrict__ bias, u16* __restrict__ O, int shift)
{
    __shared__ __align__(16) u16 lds[2][20*512];   // chunks: 0-7 A(128x32), 8-19 B(192x32)
    int tid  = threadIdx.x;
    int lane = tid & 63;
    int wid  = tid >> 6;

    int bid  = blockIdx.x;
    int swz  = (bid & 7) * 512 + (bid >> 3);
    int head = swz >> 9;           // 0..7
    int rt   = swz & 511;          // row tile 0..511
    int bt   = rt >> 5;            // batch
    int tb   = (rt & 31) * 128;    // token base within batch

    f32x4 acc[2][12];
    f32x4 zero = {0.f,0.f,0.f,0.f};
    #pragma unroll
    for (int m = 0; m < 2; m++)
        #pragma unroll
        for (int n = 0; n < 12; n++) acc[m][n] = zero;

    int rr = lane >> 2, kc = (lane & 3) * 8;
    const u16* p[5];
    int cidb = wid * 5;
    #pragma unroll
    for (int q = 0; q < 5; q++){
        int cid = cidb + q;
        if (cid < 8){
            int i   = cid*16 + rr;
            int tok = (tb + shift + i) & (TSEQ-1);
            p[q] = A + ((size_t)bt * TSEQ + tok) * KDIM + kc;
        } else {
            int cb   = cid - 8;
            int wrow = (cb >> 2) * 512 + head*64 + (cb & 3)*16 + rr;
            p[q] = Wt + (size_t)wrow * KDIM + kc;
        }
    }

    int lrow = lane & 15;
    int lk   = (lane >> 4) * 8;
    int aoff = (wid*32 + lrow) * 32 + lk;       // + m*16*32
    int boff = 8*512 + lrow*32 + lk;            // + n*16*32

    #pragma unroll
    for (int q = 0; q < 5; q++){ async_copy16(&lds[0][(cidb+q)*512], p[q]); p[q] += 32; }
    asm volatile("s_waitcnt vmcnt(0)" ::: "memory");
    __syncthreads();

    #pragma unroll
    for (int t = 0; t < NKI; t++){
        const u16* cbuf = lds[t & 1];
        u16* nbuf = (u16*)lds[(t & 1) ^ 1];
        if (t < NKI-1){
            #pragma unroll
            for (int q = 0; q < 5; q++){ async_copy16(&nbuf[(cidb+q)*512], p[q]); p[q] += 32; }
        }
        short8 af[2], bf[12];
        #pragma unroll
        for (int m = 0; m < 2; m++) af[m] = *(const short8*)(cbuf + aoff + m*512);
        #pragma unroll
        for (int n = 0; n < 12; n++) bf[n] = *(const short8*)(cbuf + boff + n*512);
        #pragma unroll
        for (int m = 0; m < 2; m++)
            #pragma unroll
            for (int n = 0; n < 12; n++)
                acc[m][n] = __builtin_amdgcn_mfma_f32_16x16x32_bf16(af[m], bf[n], acc[m][n], 0, 0, 0);
        if (t < NKI-1){
            asm volatile("s_waitcnt vmcnt(0)" ::: "memory");
            __syncthreads();
        }
    }

    // ---- attention epilogue ----
    int g_ = lane >> 4, lc = lane & 15;
    float bq[4], bk[4], bv[4];
    #pragma unroll
    for (int n = 0; n < 4; n++){
        int d = head*64 + n*16 + lc;
        bq[n] = bias[d]; bk[n] = bias[512 + d]; bv[n] = bias[1024 + d];
    }
    #pragma unroll
    for (int m = 0; m < 2; m++){
        #pragma unroll
        for (int wnd = 0; wnd < 2; wnd++){
            int ja = 2*wnd, jb = ja + 1;
            float s00=0.f, s01=0.f, s10=0.f, s11=0.f;
            #pragma unroll
            for (int n = 0; n < 4; n++){
                float qa = acc[m][n][ja] + bq[n],  qb = acc[m][n][jb] + bq[n];
                float ka = acc[m][4+n][ja] + bk[n], kb = acc[m][4+n][jb] + bk[n];
                s00 += qa*ka; s01 += qa*kb; s10 += qb*ka; s11 += qb*kb;
            }
            #pragma unroll
            for (int msk = 1; msk < 16; msk <<= 1){
                s00 += __shfl_xor(s00, msk); s01 += __shfl_xor(s01, msk);
                s10 += __shfl_xor(s10, msk); s11 += __shfl_xor(s11, msk);
            }
            s00 *= QK_SCALE; s01 *= QK_SCALE; s10 *= QK_SCALE; s11 *= QK_SCALE;
            float m0 = fmaxf(s00, s01), m1 = fmaxf(s10, s11);
            float e00 = expf(s00-m0), e01 = expf(s01-m0);
            float e10 = expf(s10-m1), e11 = expf(s11-m1);
            float ia = 1.f/(e00+e01), ib = 1.f/(e10+e11);
            float a00 = e00*ia, a01 = e01*ia, a10 = e10*ib, a11 = e11*ib;
            int ra = wid*32 + m*16 + 4*g_ + ja;
            int ta = (tb + shift + ra) & (TSEQ-1);
            size_t growa = (size_t)bt * TSEQ + ta;
            size_t growb = (size_t)bt * TSEQ + ((ta + 1) & (TSEQ-1));
            #pragma unroll
            for (int n = 0; n < 4; n++){
                float va = acc[m][8+n][ja] + bv[n], vb = acc[m][8+n][jb] + bv[n];
                int col = head*64 + n*16 + lc;
                O[growa * D_MODEL + col] = f2b(a00*va + a01*vb);
                O[growb * D_MODEL + col] = f2b(a10*va + a11*vb);
            }
        }
    }
}

// ======== gemm256: m201-style 8-phase schedule, 256x256 tile, BK=64 ========
// Per-half weights: rows >= halfM use Wt1/bias1 (pass Wt0==Wt1 for shared).
#define AOFc(buf,h) (((buf)*2+(h))*8192)
#define BOFc(buf,h) (32768 + ((buf)*2+(h))*8192)

__global__ __launch_bounds__(512, 2) void gemm256_kernel(
    const u16* __restrict__ A,
    const u16* __restrict__ Wt0, const u16* __restrict__ Wt1,
    const float* __restrict__ bias0, const float* __restrict__ bias1,
    u16* __restrict__ C, int N, int nN, int halfM)
{
    __shared__ __align__(16) u16 sh[65536];   // 128 KiB
    u16* sh_ = (u16*)sh;
    const int tid = threadIdx.x, lane = tid & 63, wid = tid >> 6;
    const int wm = wid >> 2, wn = wid & 3;
    const int cpx = (int)gridDim.x >> 3;
    const int swz = ((int)blockIdx.x & 7) * cpx + ((int)blockIdx.x >> 3);
    const int row0 = (swz / nN) * 256;
    const int col0 = (swz % nN) * 256;

    const u16*  Wt   = (row0 >= halfM) ? Wt1   : Wt0;
    const float* bias = (row0 >= halfM) ? bias1 : bias0;

    f32x4 acc[8][4];
    f32x4 zero = {0.f,0.f,0.f,0.f};
    #pragma unroll
    for (int m = 0; m < 8; m++)
        #pragma unroll
        for (int n = 0; n < 4; n++) acc[m][n] = zero;

    const int lrow = lane & 15, khi = lane >> 4;
    const int swx   = (lrow & 4) << 2;
    const int kcol0 = (khi*8) ^ swx;
    const int kcol1 = (32 + khi*8) ^ swx;
    const int aR0 = AOFc(0, wm) , aR1 = AOFc(1, wm);
    const int bh  = wn >> 1;
    const int bR0 = BOFc(0, bh), bR1 = BOFc(1, bh);
    const int abase = lrow*64;
    const int bbase = (wn & 1)*4096 + lrow*64;

    const u16* Ag = A  + (size_t)row0 * KDIM;
    const u16* Bg = Wt + (size_t)col0 * KDIM;
    const int csrc = ((lane & 7) * 8) ^ (((lane >> 3) & 4) << 2);
    const int srow = wid*16 + (lane >> 3);

    short8 af[4][2], bf[4][2];

    #define STG(dstOff, gp) { \
        const u16* s1_ = (gp) + (size_t)srow*KDIM + csrc; \
        u16* d1_ = sh_ + (dstOff) + wid*1024; \
        async_copy16(d1_, s1_); \
        async_copy16(d1_ + 512, s1_ + (size_t)8*KDIM); }
    #define RDA(bufR, h) { \
        const u16* p_ = sh_ + (bufR) + abase; \
        _Pragma("unroll") \
        for (int i_ = 0; i_ < 4; i_++){ \
            af[i_][0] = *(const short8*)(p_ + ((h)*4+i_)*1024 + kcol0); \
            af[i_][1] = *(const short8*)(p_ + ((h)*4+i_)*1024 + kcol1); } }
    #define RDB(bufR, nh) { \
        const u16* p_ = sh_ + (bufR) + bbase; \
        _Pragma("unroll") \
        for (int j_ = 0; j_ < 2; j_++){ \
            bf[(nh)*2+j_][0] = *(const short8*)(p_ + ((nh)*2+j_)*1024 + kcol0); \
            bf[(nh)*2+j_][1] = *(const short8*)(p_ + ((nh)*2+j_)*1024 + kcol1); } }
    #define MM(mh, nh) { \
        __builtin_amdgcn_s_setprio(1); \
        _Pragma("unroll") \
        for (int m_ = 0; m_ < 4; m_++) \
            _Pragma("unroll") \
            for (int n_ = 0; n_ < 2; n_++){ \
                acc[(mh)*4+m_][(nh)*2+n_] = __builtin_amdgcn_mfma_f32_16x16x32_bf16(af[m_][0], bf[(nh)*2+n_][0], acc[(mh)*4+m_][(nh)*2+n_], 0,0,0); \
                acc[(mh)*4+m_][(nh)*2+n_] = __builtin_amdgcn_mfma_f32_16x16x32_bf16(af[m_][1], bf[(nh)*2+n_][1], acc[(mh)*4+m_][(nh)*2+n_], 0,0,0); } \
        __builtin_amdgcn_s_setprio(0); }
    #define BAR() { asm volatile("" ::: "memory"); __builtin_amdgcn_s_barrier(); asm volatile("" ::: "memory"); }
    #define VMW4() asm volatile("s_waitcnt vmcnt(4)" ::: "memory")
    #define VMW0() asm volatile("s_waitcnt vmcnt(0)" ::: "memory")

    STG(BOFc(0,0), Bg);
    STG(BOFc(0,1), Bg + (size_t)128*KDIM);
    STG(AOFc(0,0), Ag);
    STG(AOFc(0,1), Ag + (size_t)128*KDIM);
    STG(BOFc(1,0), Bg + 64);
    STG(BOFc(1,1), Bg + (size_t)128*KDIM + 64);
    VMW4();
    BAR();

    #pragma unroll
    for (int i = 0; i < 4; i++){
        RDA(aR0, 0); RDB(bR0, 0);
        STG(AOFc(1,0), Ag + (2*i+1)*64);
        BAR(); MM(0,0); BAR();

        RDB(bR0, 1);
        STG(AOFc(1,1), Ag + (size_t)128*KDIM + (2*i+1)*64);
        BAR(); MM(0,1); BAR();

        RDA(aR0, 1);
        if (i < 3) STG(BOFc(0,0), Bg + (2*i+2)*64);
        BAR(); MM(1,0); BAR();

        if (i < 3){ STG(BOFc(0,1), Bg + (size_t)128*KDIM + (2*i+2)*64); VMW4(); }
        else      { VMW0(); }
        BAR(); MM(1,1); BAR();

        RDA(aR1, 0); RDB(bR1, 0);
        if (i < 3) STG(AOFc(0,0), Ag + (2*i+2)*64);
        BAR(); MM(0,0); BAR();

        RDB(bR1, 1);
        if (i < 3) STG(AOFc(0,1), Ag + (size_t)128*KDIM + (2*i+2)*64);
        BAR(); MM(0,1); BAR();

        RDA(aR1, 1);
        if (i < 3) STG(BOFc(1,0), Bg + (2*i+3)*64);
        BAR(); MM(1,0); BAR();

        if (i < 3){ STG(BOFc(1,1), Bg + (size_t)128*KDIM + (2*i+3)*64); VMW4(); }
        BAR(); MM(1,1); BAR();
    }

    int g_ = lane >> 4, lc = lane & 15;
    #pragma unroll
    for (int n = 0; n < 4; n++){
        int c = col0 + wn*64 + n*16 + lc;
        float bvv = bias[c];
        #pragma unroll
        for (int m = 0; m < 8; m++){
            int r = row0 + wm*128 + m*16 + 4*g_;
            f32x4 v = acc[m][n];
            C[(size_t)(r+0) * N + c] = f2b(v[0] + bvv);
            C[(size_t)(r+1) * N + c] = f2b(v[1] + bvv);
            C[(size_t)(r+2) * N + c] = f2b(v[2] + bvv);
            C[(size_t)(r+3) * N + c] = f2b(v[3] + bvv);
        }
    }
    #undef STG
    #undef RDA
    #undef RDB
    #undef MM
    #undef BAR
    #undef VMW4
    #undef VMW0
}

// ---- cross-attn merged: Q rows [0,2M); KV partner row = row ^ NROWS (other modality) ----
__global__ __launch_bounds__(256) void attn_cross_kernel(
    const u16* __restrict__ Q, const u16* __restrict__ KV,
    u16* __restrict__ O, int shift)
{
    int tsk  = blockIdx.x * 4 + (threadIdx.x >> 6);   // window*2 + half
    int lane = threadIdx.x & 63;
    int w  = tsk >> 1;             // 0..65535 (32 batches x 2048 windows)
    int hb = tsk & 1;
    int bt = w >> 11;              // 0..31
    int wt = w & 2047;
    int t0 = (2*wt + shift) & (TSEQ - 1);
    int t1 = (t0 + 1) & (TSEQ - 1);
    size_t g0 = (size_t)bt * TSEQ + t0;
    size_t g1 = (size_t)bt * TSEQ + t1;
    size_t kg0 = g0 ^ (size_t)NROWS;   // partner modality
    size_t kg1 = g1 ^ (size_t)NROWS;
    int col = hb*256 + lane*4;
    short4v q0 = *(const short4v*)(Q  + g0*512  + col);
    short4v q1 = *(const short4v*)(Q  + g1*512  + col);
    short4v k0 = *(const short4v*)(KV + kg0*1024 + col);
    short4v k1 = *(const short4v*)(KV + kg1*1024 + col);
    short4v v0 = *(const short4v*)(KV + kg0*1024 + 512 + col);
    short4v v1 = *(const short4v*)(KV + kg1*1024 + 512 + col);
    float s00=0.f, s01=0.f, s10=0.f, s11=0.f;
    float v0f[4], v1f[4];
    #pragma unroll
    for (int j = 0; j < 4; j++){
        float qa = b2f((u16)q0[j]), qb = b2f((u16)q1[j]);
        float ka = b2f((u16)k0[j]), kb = b2f((u16)k1[j]);
        v0f[j] = b2f((u16)v0[j]); v1f[j] = b2f((u16)v1[j]);
        s00 += qa*ka; s01 += qa*kb; s10 += qb*ka; s11 += qb*kb;
    }
    #pragma unroll
    for (int m = 1; m < 16; m <<= 1){
        s00 += __shfl_xor(s00, m); s01 += __shfl_xor(s01, m);
        s10 += __shfl_xor(s10, m); s11 += __shfl_xor(s11, m);
    }
    s00 *= QK_SCALE; s01 *= QK_SCALE; s10 *= QK_SCALE; s11 *= QK_SCALE;
    float m0 = fmaxf(s00, s01), m1 = fmaxf(s10, s11);
    float e00 = expf(s00 - m0), e01 = expf(s01 - m0);
    float e10 = expf(s10 - m1), e11 = expf(s11 - m1);
    float ia = 1.f/(e00 + e01), ib = 1.f/(e10 + e11);
    float a00 = e00*ia, a01 = e01*ia, a10 = e10*ib, a11 = e11*ib;
    short4v o0, o1;
    #pragma unroll
    for (int j = 0; j < 4; j++){
        o0[j] = (short)f2b(a00*v0f[j] + a01*v1f[j]);
        o1[j] = (short)f2b(a10*v0f[j] + a11*v1f[j]);
    }
    *(short4v*)(O + g0*512 + col) = o0;
    *(short4v*)(O + g1*512 + col) = o1;
}

// ============================== host side ==============================
extern "C" void kernel_launch(void* const* d_in, const int* in_sizes, int n_in,
                              void* d_out, int out_size, void* d_ws, size_t ws_size,
                              hipStream_t stream)
{
    const float* x = (const float*)d_in[0];
    const float* y = (const float*)d_in[1];
    const float* wa_qkv_w = (const float*)d_in[2];  const float* wa_qkv_b = (const float*)d_in[3];
    const float* wa_proj_w= (const float*)d_in[4];  const float* wa_proj_b= (const float*)d_in[5];
    const float* wa_n1g   = (const float*)d_in[6];  const float* wa_n1b   = (const float*)d_in[7];
    const float* wa_n2g   = (const float*)d_in[8];  const float* wa_n2b   = (const float*)d_in[9];
    const float* wv_qkv_w = (const float*)d_in[10]; const float* wv_qkv_b = (const float*)d_in[11];
    const float* wv_proj_w= (const float*)d_in[12]; const float* wv_proj_b= (const float*)d_in[13];
    const float* wv_n1g   = (const float*)d_in[14]; const float* wv_n1b   = (const float*)d_in[15];
    const float* wv_n2g   = (const float*)d_in[16]; const float* wv_n2b   = (const float*)d_in[17];
    const float* cm_q_w   = (const float*)d_in[18]; const float* cm_q_b   = (const float*)d_in[19];
    const float* cm_kv_w  = (const float*)d_in[20]; const float* cm_kv_b  = (const float*)d_in[21];
    const float* cm_proj_w= (const float*)d_in[22]; const float* cm_proj_b= (const float*)d_in[23];
    const float* cm_n1g   = (const float*)d_in[24]; const float* cm_n1b   = (const float*)d_in[25];
    const float* cm_n2g   = (const float*)d_in[26]; const float* cm_n2b   = (const float*)d_in[27];

    char* ws = (char*)d_ws;
    const size_t HALF = (size_t)NROWS * D_MODEL;         // elements per half
    const size_t SZ2  = (size_t)M2 * D_MODEL * 2;        // 134 MB (2M bf16)
    u16* F1b = (u16*)(ws);                    // residual stream (2M)
    u16* SFb = (u16*)(ws + 1*SZ2);            // self outputs [x;y]
    u16* SLN = (u16*)(ws + 2*SZ2);            // LN(cm_n1) of self outputs; CN aliases
    u16* XN  = (u16*)(ws + 3*SZ2);            // ln-out / Qall / P
    u16* O   = (u16*)(ws + 4*SZ2);            // attn outputs
    u16* KVA = (u16*)(ws + 5*SZ2);            // 2M x 1024 (cross); PB aliases (self)
    u16* WB  = (u16*)(ws + 7*SZ2);

    u16* CN = SLN;                 // alias: SLN dead after q-gemm #1
    u16* PB = KVA;                 // proj-output scratch during self phase

    u16* wa_qkv_t  = WB;
    u16* wa_proj_t = wa_qkv_t  + 1536*512;
    u16* wv_qkv_t  = wa_proj_t + 512*512;
    u16* wv_proj_t = wv_qkv_t  + 1536*512;
    u16* cm_q_t    = wv_proj_t + 512*512;
    u16* cm_kv_t   = cm_q_t    + 512*512;
    u16* cm_proj_t = cm_kv_t   + 1024*512;

    // all 7 weight transposes in one dispatch (3145728 elems)
    wconv_all_kernel<<<12288, 256, 0, stream>>>(
        wa_qkv_w, wa_proj_w, wv_qkv_w, wv_proj_w, cm_q_w, cm_kv_w, cm_proj_w, wa_qkv_t);

    const int lnGridH   = NROWS / 4;          // per-half ln/resln grid
    const int rlGrid2   = M2 / 4;             // merged resln grid
    const int attnGrid2 = M2 / 2 * 2 / 4;     // 32768
    const int qaGridH   = (NROWS / 128) * NH; // 4096, per-half

    auto gemm = [&](const u16* Ain, const u16* W0, const u16* W1,
                    const float* b0, const float* b1, u16* Cout, int N, int halfM){
        int nN = N / 256;
        gemm256_kernel<<<(M2/256) * nN, 512, 0, stream>>>(Ain, W0, W1, b0, b1, Cout, N, nN, halfM);
    };

    // ================= self phase (per-half qkvattn; merged gemm/resln) =================
    ln_kernel<<<lnGridH, 256, 0, stream>>>(x, wa_n1g, wa_n1b, XN);
    ln_kernel<<<lnGridH, 256, 0, stream>>>(y, wv_n1g, wv_n1b, XN + HALF);

    qkvattn_kernel<<<qaGridH, 256, 0, stream>>>(XN,        wa_qkv_t, wa_qkv_b, O,        0);
    qkvattn_kernel<<<qaGridH, 256, 0, stream>>>(XN + HALF, wv_qkv_t, wv_qkv_b, O + HALF, 0);
    gemm(O, wa_proj_t, wv_proj_t, wa_proj_b, wv_proj_b, PB, 512, NROWS);
    resln_kernel<0,1><<<lnGridH, 256, 0, stream>>>(PB,        x, nullptr, wa_n2g, wa_n2b, F1b,        XN,        wa_n1g, wa_n1b);
    resln_kernel<0,1><<<lnGridH, 256, 0, stream>>>(PB + HALF, y, nullptr, wv_n2g, wv_n2b, F1b + HALF, XN + HALF, wv_n1g, wv_n1b);

    qkvattn_kernel<<<qaGridH, 256, 0, stream>>>(XN,        wa_qkv_t, wa_qkv_b, O,        1);
    qkvattn_kernel<<<qaGridH, 256, 0, stream>>>(XN + HALF, wv_qkv_t, wv_qkv_b, O + HALF, 1);
    gemm(O, wa_proj_t, wv_proj_t, wa_proj_b, wv_proj_b, PB, 512, NROWS);
    resln_kernel<1,1><<<lnGridH, 256, 0, stream>>>(PB,        F1b,        nullptr, wa_n2g, wa_n2b, SFb,        SLN,        cm_n1g, cm_n1b);
    resln_kernel<1,1><<<lnGridH, 256, 0, stream>>>(PB + HALF, F1b + HALF, nullptr, wv_n2g, wv_n2b, SFb + HALF, SLN + HALF, cm_n1g, cm_n1b);

    // ================= cross phase (fully merged; shared cm weights) =================
    float* outF = (float*)d_out;   // 2M rows fp32, [x-result; y-result] contiguous

    gemm(SLN, cm_kv_t, cm_kv_t, cm_kv_b, cm_kv_b, KVA, 1024, M2);       // KV once, both modalities
    gemm(SLN, cm_q_t,  cm_q_t,  cm_q_b,  cm_q_b,  XN,  512,  M2);       // Q all
    attn_cross_kernel<<<attnGrid2, 256, 0, stream>>>(XN, KVA, O, 0);
    gemm(O, cm_proj_t, cm_proj_t, cm_proj_b, cm_proj_b, XN, 512, M2);
    resln_kernel<1,1><<<rlGrid2, 256, 0, stream>>>(XN, SFb, nullptr, cm_n2g, cm_n2b, F1b, CN, cm_n1g, cm_n1b);

    gemm(CN, cm_q_t, cm_q_t, cm_q_b, cm_q_b, XN, 512, M2);
    attn_cross_kernel<<<attnGrid2, 256, 0, stream>>>(XN, KVA, O, 1);
    gemm(O, cm_proj_t, cm_proj_t, cm_proj_b, cm_proj_b, XN, 512, M2);
    resln_kernel<1,0><<<rlGrid2, 256, 0, stream>>>(XN, F1b, SFb, cm_n2g, cm_n2b, outF, nullptr, nullptr, nullptr);
}

// Round 14
// 2017.302 us; speedup vs baseline: 1.2443x; 1.0962x over previous
//
#include <hip/hip_runtime.h>

typedef unsigned short u16;
typedef unsigned int u32;
typedef __attribute__((ext_vector_type(8))) short short8;
typedef __attribute__((ext_vector_type(4))) short short4v;
typedef __attribute__((ext_vector_type(4))) float f32x4;

#define D_MODEL 512
#define NH 8
#define TSEQ 4096
#define NB 16
#define NROWS (NB*TSEQ)          // 65536 tokens per modality
#define M2 (2*NROWS)             // 131072 merged rows
#define QK_SCALE 0.125f          // DH^-0.5 / TEMP
#define KDIM 512
#define NKI (KDIM/32)            // 16 K-iterations of BK=32

__device__ __forceinline__ float b2f(u16 u){
    union { float f; unsigned int i; } v; v.i = ((unsigned int)u) << 16; return v.f;
}
__device__ __forceinline__ u16 f2b(float f){
    union { float f; unsigned int i; } v; v.f = f;
    unsigned int r = v.i + 0x7FFFu + ((v.i >> 16) & 1u);   // RNE
    return (u16)(r >> 16);
}

// async global->LDS, 16B/lane; LDS dest = wave-uniform base + lane*16
__device__ __forceinline__ void async_copy16(u16* lds, const u16* g){
    __builtin_amdgcn_global_load_lds(
        (const __attribute__((address_space(1))) u32*)g,
        (__attribute__((address_space(3))) u32*)lds, 16, 0, 0);
}

// ------- weight convert, ALL weights in one dispatch: W_i (512 x N_i fp32) -> dst (N_i x 512 bf16) ----
__global__ void wconv_all_kernel(
    const float* __restrict__ s0, const float* __restrict__ s1,
    const float* __restrict__ s2, const float* __restrict__ s3,
    const float* __restrict__ s4, const float* __restrict__ s5,
    const float* __restrict__ s6, u16* __restrict__ dst)
{
    int idx = blockIdx.x * 256 + threadIdx.x;     // < 3145728
    int off = idx;
    const float* W; int N;
    if      (off < 786432)                    { W = s0; N = 1536; }
    else if ((off -= 786432) < 262144)        { W = s1; N = 512;  }
    else if ((off -= 262144) < 786432)        { W = s2; N = 1536; }
    else if ((off -= 786432) < 262144)        { W = s3; N = 512;  }
    else if ((off -= 262144) < 262144)        { W = s4; N = 512;  }
    else if ((off -= 262144) < 524288)        { W = s5; N = 1024; }
    else    { off -= 524288;                    W = s6; N = 512;  }
    int n = off >> 9;
    int k = off & 511;
    dst[idx] = f2b(W[(size_t)k * N + n]);
}

// ---------------- LayerNorm: fp32 in -> bf16 out (one wave per row) ----------------
__global__ __launch_bounds__(256) void ln_kernel(
    const float* __restrict__ X, const float* __restrict__ g,
    const float* __restrict__ b, u16* __restrict__ out)
{
    int row  = blockIdx.x * 4 + (threadIdx.x >> 6);
    int lane = threadIdx.x & 63;
    size_t base = (size_t)row * D_MODEL + lane * 8;
    float4 x0 = *(const float4*)(X + base);
    float4 x1 = *(const float4*)(X + base + 4);
    float t[8] = {x0.x,x0.y,x0.z,x0.w,x1.x,x1.y,x1.z,x1.w};
    float s = 0.f, ss = 0.f;
    #pragma unroll
    for (int j = 0; j < 8; j++){ s += t[j]; ss += t[j]*t[j]; }
    #pragma unroll
    for (int m = 1; m < 64; m <<= 1){ s += __shfl_xor(s, m); ss += __shfl_xor(ss, m); }
    float mean = s * (1.f/D_MODEL);
    float var  = ss * (1.f/D_MODEL) - mean*mean;
    float rst  = rsqrtf(var + 1e-5f);
    float4 g0 = *(const float4*)(g + lane*8);
    float4 g1 = *(const float4*)(g + lane*8 + 4);
    float4 c0 = *(const float4*)(b + lane*8);
    float4 c1 = *(const float4*)(b + lane*8 + 4);
    float gv[8] = {g0.x,g0.y,g0.z,g0.w,g1.x,g1.y,g1.z,g1.w};
    float bv[8] = {c0.x,c0.y,c0.z,c0.w,c1.x,c1.y,c1.z,c1.w};
    short8 o;
    #pragma unroll
    for (int j = 0; j < 8; j++) o[j] = (short)f2b((t[j]-mean)*rst*gv[j] + bv[j]);
    *(short8*)(out + base) = o;
}

// ------- residual + LN, templated on Xin/out dtype (+opt bf16 Add, +opt next-LN) ----
template<int XINBF, int OUTBF>
__global__ __launch_bounds__(256) void resln_kernel(
    const u16* __restrict__ P, const void* __restrict__ Xin,
    const u16* __restrict__ Add,
    const float* __restrict__ g, const float* __restrict__ b,
    void* __restrict__ out,
    u16* __restrict__ lnout, const float* __restrict__ g2, const float* __restrict__ b2)
{
    int row  = blockIdx.x * 4 + (threadIdx.x >> 6);
    int lane = threadIdx.x & 63;
    size_t base = (size_t)row * D_MODEL + lane * 8;
    short8 pv = *(const short8*)(P + base);
    float t[8];
    if constexpr (XINBF){
        short8 xv = *(const short8*)((const u16*)Xin + base);
        #pragma unroll
        for (int j = 0; j < 8; j++) t[j] = b2f((u16)pv[j]) + b2f((u16)xv[j]);
    } else {
        float4 x0 = *(const float4*)((const float*)Xin + base);
        float4 x1 = *(const float4*)((const float*)Xin + base + 4);
        float xr[8] = {x0.x,x0.y,x0.z,x0.w,x1.x,x1.y,x1.z,x1.w};
        #pragma unroll
        for (int j = 0; j < 8; j++) t[j] = b2f((u16)pv[j]) + xr[j];
    }
    float s = 0.f, ss = 0.f;
    #pragma unroll
    for (int j = 0; j < 8; j++){ s += t[j]; ss += t[j]*t[j]; }
    #pragma unroll
    for (int m = 1; m < 64; m <<= 1){ s += __shfl_xor(s, m); ss += __shfl_xor(ss, m); }
    float mean = s * (1.f/D_MODEL);
    float var  = ss * (1.f/D_MODEL) - mean*mean;
    float rst  = rsqrtf(var + 1e-5f);
    float4 g0 = *(const float4*)(g + lane*8);
    float4 g1 = *(const float4*)(g + lane*8 + 4);
    float4 c0 = *(const float4*)(b + lane*8);
    float4 c1 = *(const float4*)(b + lane*8 + 4);
    float gv[8] = {g0.x,g0.y,g0.z,g0.w,g1.x,g1.y,g1.z,g1.w};
    float bv[8] = {c0.x,c0.y,c0.z,c0.w,c1.x,c1.y,c1.z,c1.w};
    float o[8];
    #pragma unroll
    for (int j = 0; j < 8; j++) o[j] = (t[j]-mean)*rst*gv[j] + bv[j];

    if (lnout){
        float s2 = 0.f, ss2 = 0.f;
        #pragma unroll
        for (int j = 0; j < 8; j++){ s2 += o[j]; ss2 += o[j]*o[j]; }
        #pragma unroll
        for (int m = 1; m < 64; m <<= 1){ s2 += __shfl_xor(s2, m); ss2 += __shfl_xor(ss2, m); }
        float mean2 = s2 * (1.f/D_MODEL);
        float var2  = ss2 * (1.f/D_MODEL) - mean2*mean2;
        float rst2  = rsqrtf(var2 + 1e-5f);
        float4 g20 = *(const float4*)(g2 + lane*8);
        float4 g21 = *(const float4*)(g2 + lane*8 + 4);
        float4 b20 = *(const float4*)(b2 + lane*8);
        float4 b21 = *(const float4*)(b2 + lane*8 + 4);
        float g2v[8] = {g20.x,g20.y,g20.z,g20.w,g21.x,g21.y,g21.z,g21.w};
        float b2v[8] = {b20.x,b20.y,b20.z,b20.w,b21.x,b21.y,b21.z,b21.w};
        short8 lo;
        #pragma unroll
        for (int j = 0; j < 8; j++) lo[j] = (short)f2b((o[j]-mean2)*rst2*g2v[j] + b2v[j]);
        *(short8*)(lnout + base) = lo;
    }
    if (Add){
        short8 av = *(const short8*)(Add + base);
        #pragma unroll
        for (int j = 0; j < 8; j++) o[j] += b2f((u16)av[j]);
    }
    if constexpr (OUTBF){
        short8 ov;
        #pragma unroll
        for (int j = 0; j < 8; j++) ov[j] = (short)f2b(o[j]);
        *(short8*)((u16*)out + base) = ov;
    } else {
        float4 r0 = {o[0],o[1],o[2],o[3]};
        float4 r1 = {o[4],o[5],o[6],o[7]};
        *(float4*)((float*)out + base)     = r0;
        *(float4*)((float*)out + base + 4) = r1;
    }
}

// ======== fused QKV-GEMM + window attention (WIN=2), single modality (R10-proven) ========
__global__ __launch_bounds__(256) void qkvattn_kernel(
    const u16* __restrict__ A, const u16* __restrict__ Wt,
    const float* __restrict__ bias, u16* __restrict__ O, int shift)
{
    __shared__ __align__(16) u16 lds[2][20*512];   // chunks: 0-7 A(128x32), 8-19 B(192x32)
    int tid  = threadIdx.x;
    int lane = tid & 63;
    int wid  = tid >> 6;

    int bid  = blockIdx.x;
    int swz  = (bid & 7) * 512 + (bid >> 3);
    int head = swz >> 9;           // 0..7
    int rt   = swz & 511;          // row tile 0..511
    int bt   = rt >> 5;            // batch
    int tb   = (rt & 31) * 128;    // token base within batch

    f32x4 acc[2][12];
    f32x4 zero = {0.f,0.f,0.f,0.f};
    #pragma unroll
    for (int m = 0; m < 2; m++)
        #pragma unroll
        for (int n = 0; n < 12; n++) acc[m][n] = zero;

    int rr = lane >> 2, kc = (lane & 3) * 8;
    const u16* p[5];
    int cidb = wid * 5;
    #pragma unroll
    for (int q = 0; q < 5; q++){
        int cid = cidb + q;
        if (cid < 8){
            int i   = cid*16 + rr;
            int tok = (tb + shift + i) & (TSEQ-1);
            p[q] = A + ((size_t)bt * TSEQ + tok) * KDIM + kc;
        } else {
            int cb   = cid - 8;
            int wrow = (cb >> 2) * 512 + head*64 + (cb & 3)*16 + rr;
            p[q] = Wt + (size_t)wrow * KDIM + kc;
        }
    }

    int lrow = lane & 15;
    int lk   = (lane >> 4) * 8;
    int aoff = (wid*32 + lrow) * 32 + lk;       // + m*16*32
    int boff = 8*512 + lrow*32 + lk;            // + n*16*32

    #pragma unroll
    for (int q = 0; q < 5; q++){ async_copy16(&lds[0][(cidb+q)*512], p[q]); p[q] += 32; }
    asm volatile("s_waitcnt vmcnt(0)" ::: "memory");
    __syncthreads();

    #pragma unroll
    for (int t = 0; t < NKI; t++){
        const u16* cbuf = lds[t & 1];
        u16* nbuf = (u16*)lds[(t & 1) ^ 1];
        if (t < NKI-1){
            #pragma unroll
            for (int q = 0; q < 5; q++){ async_copy16(&nbuf[(cidb+q)*512], p[q]); p[q] += 32; }
        }
        short8 af[2], bf[12];
        #pragma unroll
        for (int m = 0; m < 2; m++) af[m] = *(const short8*)(cbuf + aoff + m*512);
        #pragma unroll
        for (int n = 0; n < 12; n++) bf[n] = *(const short8*)(cbuf + boff + n*512);
        #pragma unroll
        for (int m = 0; m < 2; m++)
            #pragma unroll
            for (int n = 0; n < 12; n++)
                acc[m][n] = __builtin_amdgcn_mfma_f32_16x16x32_bf16(af[m], bf[n], acc[m][n], 0, 0, 0);
        if (t < NKI-1){
            asm volatile("s_waitcnt vmcnt(0)" ::: "memory");
            __syncthreads();
        }
    }

    // ---- attention epilogue ----
    int g_ = lane >> 4, lc = lane & 15;
    float bq[4], bk[4], bv[4];
    #pragma unroll
    for (int n = 0; n < 4; n++){
        int d = head*64 + n*16 + lc;
        bq[n] = bias[d]; bk[n] = bias[512 + d]; bv[n] = bias[1024 + d];
    }
    #pragma unroll
    for (int m = 0; m < 2; m++){
        #pragma unroll
        for (int wnd = 0; wnd < 2; wnd++){
            int ja = 2*wnd, jb = ja + 1;
            float s00=0.f, s01=0.f, s10=0.f, s11=0.f;
            #pragma unroll
            for (int n = 0; n < 4; n++){
                float qa = acc[m][n][ja] + bq[n],  qb = acc[m][n][jb] + bq[n];
                float ka = acc[m][4+n][ja] + bk[n], kb = acc[m][4+n][jb] + bk[n];
                s00 += qa*ka; s01 += qa*kb; s10 += qb*ka; s11 += qb*kb;
            }
            #pragma unroll
            for (int msk = 1; msk < 16; msk <<= 1){
                s00 += __shfl_xor(s00, msk); s01 += __shfl_xor(s01, msk);
                s10 += __shfl_xor(s10, msk); s11 += __shfl_xor(s11, msk);
            }
            s00 *= QK_SCALE; s01 *= QK_SCALE; s10 *= QK_SCALE; s11 *= QK_SCALE;
            float m0 = fmaxf(s00, s01), m1 = fmaxf(s10, s11);
            float e00 = expf(s00-m0), e01 = expf(s01-m0);
            float e10 = expf(s10-m1), e11 = expf(s11-m1);
            float ia = 1.f/(e00+e01), ib = 1.f/(e10+e11);
            float a00 = e00*ia, a01 = e01*ia, a10 = e10*ib, a11 = e11*ib;
            int ra = wid*32 + m*16 + 4*g_ + ja;
            int ta = (tb + shift + ra) & (TSEQ-1);
            size_t growa = (size_t)bt * TSEQ + ta;
            size_t growb = (size_t)bt * TSEQ + ((ta + 1) & (TSEQ-1));
            #pragma unroll
            for (int n = 0; n < 4; n++){
                float va = acc[m][8+n][ja] + bv[n], vb = acc[m][8+n][jb] + bv[n];
                int col = head*64 + n*16 + lc;
                O[growa * D_MODEL + col] = f2b(a00*va + a01*vb);
                O[growb * D_MODEL + col] = f2b(a10*va + a11*vb);
            }
        }
    }
}

// ======== gemm256: m201-style 8-phase schedule, 256x256 tile, BK=64 ========
// Per-half weights: rows >= halfM use Wt1/bias1 (pass Wt0==Wt1 for shared).
// Epilogue stores n-INNER so each output row's 4x32B quarter-line segments issue
// back-to-back (one full 128B line per lane-quarter) -> no partial-line RMW.
#define AOFc(buf,h) (((buf)*2+(h))*8192)
#define BOFc(buf,h) (32768 + ((buf)*2+(h))*8192)

__global__ __launch_bounds__(512, 2) void gemm256_kernel(
    const u16* __restrict__ A,
    const u16* __restrict__ Wt0, const u16* __restrict__ Wt1,
    const float* __restrict__ bias0, const float* __restrict__ bias1,
    u16* __restrict__ C, int N, int nN, int halfM)
{
    __shared__ __align__(16) u16 sh[65536];   // 128 KiB
    u16* sh_ = (u16*)sh;
    const int tid = threadIdx.x, lane = tid & 63, wid = tid >> 6;
    const int wm = wid >> 2, wn = wid & 3;
    const int cpx = (int)gridDim.x >> 3;
    const int swz = ((int)blockIdx.x & 7) * cpx + ((int)blockIdx.x >> 3);
    const int row0 = (swz / nN) * 256;
    const int col0 = (swz % nN) * 256;

    const u16*  Wt   = (row0 >= halfM) ? Wt1   : Wt0;
    const float* bias = (row0 >= halfM) ? bias1 : bias0;

    f32x4 acc[8][4];
    f32x4 zero = {0.f,0.f,0.f,0.f};
    #pragma unroll
    for (int m = 0; m < 8; m++)
        #pragma unroll
        for (int n = 0; n < 4; n++) acc[m][n] = zero;

    const int lrow = lane & 15, khi = lane >> 4;
    const int swx   = (lrow & 4) << 2;
    const int kcol0 = (khi*8) ^ swx;
    const int kcol1 = (32 + khi*8) ^ swx;
    const int aR0 = AOFc(0, wm) , aR1 = AOFc(1, wm);
    const int bh  = wn >> 1;
    const int bR0 = BOFc(0, bh), bR1 = BOFc(1, bh);
    const int abase = lrow*64;
    const int bbase = (wn & 1)*4096 + lrow*64;

    const u16* Ag = A  + (size_t)row0 * KDIM;
    const u16* Bg = Wt + (size_t)col0 * KDIM;
    const int csrc = ((lane & 7) * 8) ^ (((lane >> 3) & 4) << 2);
    const int srow = wid*16 + (lane >> 3);

    short8 af[4][2], bf[4][2];

    #define STG(dstOff, gp) { \
        const u16* s1_ = (gp) + (size_t)srow*KDIM + csrc; \
        u16* d1_ = sh_ + (dstOff) + wid*1024; \
        async_copy16(d1_, s1_); \
        async_copy16(d1_ + 512, s1_ + (size_t)8*KDIM); }
    #define RDA(bufR, h) { \
        const u16* p_ = sh_ + (bufR) + abase; \
        _Pragma("unroll") \
        for (int i_ = 0; i_ < 4; i_++){ \
            af[i_][0] = *(const short8*)(p_ + ((h)*4+i_)*1024 + kcol0); \
            af[i_][1] = *(const short8*)(p_ + ((h)*4+i_)*1024 + kcol1); } }
    #define RDB(bufR, nh) { \
        const u16* p_ = sh_ + (bufR) + bbase; \
        _Pragma("unroll") \
        for (int j_ = 0; j_ < 2; j_++){ \
            bf[(nh)*2+j_][0] = *(const short8*)(p_ + ((nh)*2+j_)*1024 + kcol0); \
            bf[(nh)*2+j_][1] = *(const short8*)(p_ + ((nh)*2+j_)*1024 + kcol1); } }
    #define MM(mh, nh) { \
        __builtin_amdgcn_s_setprio(1); \
        _Pragma("unroll") \
        for (int m_ = 0; m_ < 4; m_++) \
            _Pragma("unroll") \
            for (int n_ = 0; n_ < 2; n_++){ \
                acc[(mh)*4+m_][(nh)*2+n_] = __builtin_amdgcn_mfma_f32_16x16x32_bf16(af[m_][0], bf[(nh)*2+n_][0], acc[(mh)*4+m_][(nh)*2+n_], 0,0,0); \
                acc[(mh)*4+m_][(nh)*2+n_] = __builtin_amdgcn_mfma_f32_16x16x32_bf16(af[m_][1], bf[(nh)*2+n_][1], acc[(mh)*4+m_][(nh)*2+n_], 0,0,0); } \
        __builtin_amdgcn_s_setprio(0); }
    #define BAR() { asm volatile("" ::: "memory"); __builtin_amdgcn_s_barrier(); asm volatile("" ::: "memory"); }
    #define VMW4() asm volatile("s_waitcnt vmcnt(4)" ::: "memory")
    #define VMW0() asm volatile("s_waitcnt vmcnt(0)" ::: "memory")

    STG(BOFc(0,0), Bg);
    STG(BOFc(0,1), Bg + (size_t)128*KDIM);
    STG(AOFc(0,0), Ag);
    STG(AOFc(0,1), Ag + (size_t)128*KDIM);
    STG(BOFc(1,0), Bg + 64);
    STG(BOFc(1,1), Bg + (size_t)128*KDIM + 64);
    VMW4();
    BAR();

    #pragma unroll
    for (int i = 0; i < 4; i++){
        RDA(aR0, 0); RDB(bR0, 0);
        STG(AOFc(1,0), Ag + (2*i+1)*64);
        BAR(); MM(0,0); BAR();

        RDB(bR0, 1);
        STG(AOFc(1,1), Ag + (size_t)128*KDIM + (2*i+1)*64);
        BAR(); MM(0,1); BAR();

        RDA(aR0, 1);
        if (i < 3) STG(BOFc(0,0), Bg + (2*i+2)*64);
        BAR(); MM(1,0); BAR();

        if (i < 3){ STG(BOFc(0,1), Bg + (size_t)128*KDIM + (2*i+2)*64); VMW4(); }
        else      { VMW0(); }
        BAR(); MM(1,1); BAR();

        RDA(aR1, 0); RDB(bR1, 0);
        if (i < 3) STG(AOFc(0,0), Ag + (2*i+2)*64);
        BAR(); MM(0,0); BAR();

        RDB(bR1, 1);
        if (i < 3) STG(AOFc(0,1), Ag + (size_t)128*KDIM + (2*i+2)*64);
        BAR(); MM(0,1); BAR();

        RDA(aR1, 1);
        if (i < 3) STG(BOFc(1,0), Bg + (2*i+3)*64);
        BAR(); MM(1,0); BAR();

        if (i < 3){ STG(BOFc(1,1), Bg + (size_t)128*KDIM + (2*i+3)*64); VMW4(); }
        BAR(); MM(1,1); BAR();
    }

    // epilogue: bias + bf16 store, n-inner (row-contiguous 128B per lane-quarter)
    int g_ = lane >> 4, lc = lane & 15;
    float bvv[4];
    #pragma unroll
    for (int n = 0; n < 4; n++) bvv[n] = bias[col0 + wn*64 + n*16 + lc];
    #pragma unroll
    for (int m = 0; m < 8; m++){
        int rbase = row0 + wm*128 + m*16 + 4*g_;
        #pragma unroll
        for (int j = 0; j < 4; j++){
            size_t rowoff = (size_t)(rbase + j) * N + col0 + wn*64 + lc;
            #pragma unroll
            for (int n = 0; n < 4; n++)
                C[rowoff + n*16] = f2b(acc[m][n][j] + bvv[n]);
        }
    }
    #undef STG
    #undef RDA
    #undef RDB
    #undef MM
    #undef BAR
    #undef VMW4
    #undef VMW0
}

// ---- cross-attn merged: Q rows [0,2M); KV partner row = row ^ NROWS (other modality) ----
__global__ __launch_bounds__(256) void attn_cross_kernel(
    const u16* __restrict__ Q, const u16* __restrict__ KV,
    u16* __restrict__ O, int shift)
{
    int tsk  = blockIdx.x * 4 + (threadIdx.x >> 6);   // window*2 + half
    int lane = threadIdx.x & 63;
    int w  = tsk >> 1;             // 0..65535 (32 batches x 2048 windows)
    int hb = tsk & 1;
    int bt = w >> 11;              // 0..31
    int wt = w & 2047;
    int t0 = (2*wt + shift) & (TSEQ - 1);
    int t1 = (t0 + 1) & (TSEQ - 1);
    size_t g0 = (size_t)bt * TSEQ + t0;
    size_t g1 = (size_t)bt * TSEQ + t1;
    size_t kg0 = g0 ^ (size_t)NROWS;   // partner modality
    size_t kg1 = g1 ^ (size_t)NROWS;
    int col = hb*256 + lane*4;
    short4v q0 = *(const short4v*)(Q  + g0*512  + col);
    short4v q1 = *(const short4v*)(Q  + g1*512  + col);
    short4v k0 = *(const short4v*)(KV + kg0*1024 + col);
    short4v k1 = *(const short4v*)(KV + kg1*1024 + col);
    short4v v0 = *(const short4v*)(KV + kg0*1024 + 512 + col);
    short4v v1 = *(const short4v*)(KV + kg1*1024 + 512 + col);
    float s00=0.f, s01=0.f, s10=0.f, s11=0.f;
    float v0f[4], v1f[4];
    #pragma unroll
    for (int j = 0; j < 4; j++){
        float qa = b2f((u16)q0[j]), qb = b2f((u16)q1[j]);
        float ka = b2f((u16)k0[j]), kb = b2f((u16)k1[j]);
        v0f[j] = b2f((u16)v0[j]); v1f[j] = b2f((u16)v1[j]);
        s00 += qa*ka; s01 += qa*kb; s10 += qb*ka; s11 += qb*kb;
    }
    #pragma unroll
    for (int m = 1; m < 16; m <<= 1){
        s00 += __shfl_xor(s00, m); s01 += __shfl_xor(s01, m);
        s10 += __shfl_xor(s10, m); s11 += __shfl_xor(s11, m);
    }
    s00 *= QK_SCALE; s01 *= QK_SCALE; s10 *= QK_SCALE; s11 *= QK_SCALE;
    float m0 = fmaxf(s00, s01), m1 = fmaxf(s10, s11);
    float e00 = expf(s00 - m0), e01 = expf(s01 - m0);
    float e10 = expf(s10 - m1), e11 = expf(s11 - m1);
    float ia = 1.f/(e00 + e01), ib = 1.f/(e10 + e11);
    float a00 = e00*ia, a01 = e01*ia, a10 = e10*ib, a11 = e11*ib;
    short4v o0, o1;
    #pragma unroll
    for (int j = 0; j < 4; j++){
        o0[j] = (short)f2b(a00*v0f[j] + a01*v1f[j]);
        o1[j] = (short)f2b(a10*v0f[j] + a11*v1f[j]);
    }
    *(short4v*)(O + g0*512 + col) = o0;
    *(short4v*)(O + g1*512 + col) = o1;
}

// ============================== host side ==============================
extern "C" void kernel_launch(void* const* d_in, const int* in_sizes, int n_in,
                              void* d_out, int out_size, void* d_ws, size_t ws_size,
                              hipStream_t stream)
{
    const float* x = (const float*)d_in[0];
    const float* y = (const float*)d_in[1];
    const float* wa_qkv_w = (const float*)d_in[2];  const float* wa_qkv_b = (const float*)d_in[3];
    const float* wa_proj_w= (const float*)d_in[4];  const float* wa_proj_b= (const float*)d_in[5];
    const float* wa_n1g   = (const float*)d_in[6];  const float* wa_n1b   = (const float*)d_in[7];
    const float* wa_n2g   = (const float*)d_in[8];  const float* wa_n2b   = (const float*)d_in[9];
    const float* wv_qkv_w = (const float*)d_in[10]; const float* wv_qkv_b = (const float*)d_in[11];
    const float* wv_proj_w= (const float*)d_in[12]; const float* wv_proj_b= (const float*)d_in[13];
    const float* wv_n1g   = (const float*)d_in[14]; const float* wv_n1b   = (const float*)d_in[15];
    const float* wv_n2g   = (const float*)d_in[16]; const float* wv_n2b   = (const float*)d_in[17];
    const float* cm_q_w   = (const float*)d_in[18]; const float* cm_q_b   = (const float*)d_in[19];
    const float* cm_kv_w  = (const float*)d_in[20]; const float* cm_kv_b  = (const float*)d_in[21];
    const float* cm_proj_w= (const float*)d_in[22]; const float* cm_proj_b= (const float*)d_in[23];
    const float* cm_n1g   = (const float*)d_in[24]; const float* cm_n1b   = (const float*)d_in[25];
    const float* cm_n2g   = (const float*)d_in[26]; const float* cm_n2b   = (const float*)d_in[27];

    char* ws = (char*)d_ws;
    const size_t HALF = (size_t)NROWS * D_MODEL;         // elements per half
    const size_t SZ2  = (size_t)M2 * D_MODEL * 2;        // 134 MB (2M bf16)
    u16* F1b = (u16*)(ws);                    // residual stream (2M)
    u16* SFb = (u16*)(ws + 1*SZ2);            // self outputs [x;y]
    u16* SLN = (u16*)(ws + 2*SZ2);            // LN(cm_n1) of self outputs; CN aliases
    u16* XN  = (u16*)(ws + 3*SZ2);            // ln-out / Qall / P
    u16* O   = (u16*)(ws + 4*SZ2);            // attn outputs
    u16* KVA = (u16*)(ws + 5*SZ2);            // 2M x 1024 (cross); PB aliases (self)
    u16* WB  = (u16*)(ws + 7*SZ2);

    u16* CN = SLN;                 // alias: SLN dead after q-gemm #1
    u16* PB = KVA;                 // proj-output scratch during self phase

    u16* wa_qkv_t  = WB;
    u16* wa_proj_t = wa_qkv_t  + 1536*512;
    u16* wv_qkv_t  = wa_proj_t + 512*512;
    u16* wv_proj_t = wv_qkv_t  + 1536*512;
    u16* cm_q_t    = wv_proj_t + 512*512;
    u16* cm_kv_t   = cm_q_t    + 512*512;
    u16* cm_proj_t = cm_kv_t   + 1024*512;

    // all 7 weight transposes in one dispatch (3145728 elems)
    wconv_all_kernel<<<12288, 256, 0, stream>>>(
        wa_qkv_w, wa_proj_w, wv_qkv_w, wv_proj_w, cm_q_w, cm_kv_w, cm_proj_w, wa_qkv_t);

    const int lnGridH   = NROWS / 4;          // per-half ln/resln grid
    const int rlGrid2   = M2 / 4;             // merged resln grid
    const int attnGrid2 = M2 / 2 * 2 / 4;     // 32768
    const int qaGridH   = (NROWS / 128) * NH; // 4096, per-half

    auto gemm = [&](const u16* Ain, const u16* W0, const u16* W1,
                    const float* b0, const float* b1, u16* Cout, int N, int halfM){
        int nN = N / 256;
        gemm256_kernel<<<(M2/256) * nN, 512, 0, stream>>>(Ain, W0, W1, b0, b1, Cout, N, nN, halfM);
    };

    // ================= self phase (per-half qkvattn; merged gemm/resln) =================
    ln_kernel<<<lnGridH, 256, 0, stream>>>(x, wa_n1g, wa_n1b, XN);
    ln_kernel<<<lnGridH, 256, 0, stream>>>(y, wv_n1g, wv_n1b, XN + HALF);

    qkvattn_kernel<<<qaGridH, 256, 0, stream>>>(XN,        wa_qkv_t, wa_qkv_b, O,        0);
    qkvattn_kernel<<<qaGridH, 256, 0, stream>>>(XN + HALF, wv_qkv_t, wv_qkv_b, O + HALF, 0);
    gemm(O, wa_proj_t, wv_proj_t, wa_proj_b, wv_proj_b, PB, 512, NROWS);
    resln_kernel<0,1><<<lnGridH, 256, 0, stream>>>(PB,        x, nullptr, wa_n2g, wa_n2b, F1b,        XN,        wa_n1g, wa_n1b);
    resln_kernel<0,1><<<lnGridH, 256, 0, stream>>>(PB + HALF, y, nullptr, wv_n2g, wv_n2b, F1b + HALF, XN + HALF, wv_n1g, wv_n1b);

    qkvattn_kernel<<<qaGridH, 256, 0, stream>>>(XN,        wa_qkv_t, wa_qkv_b, O,        1);
    qkvattn_kernel<<<qaGridH, 256, 0, stream>>>(XN + HALF, wv_qkv_t, wv_qkv_b, O + HALF, 1);
    gemm(O, wa_proj_t, wv_proj_t, wa_proj_b, wv_proj_b, PB, 512, NROWS);
    resln_kernel<1,1><<<lnGridH, 256, 0, stream>>>(PB,        F1b,        nullptr, wa_n2g, wa_n2b, SFb,        SLN,        cm_n1g, cm_n1b);
    resln_kernel<1,1><<<lnGridH, 256, 0, stream>>>(PB + HALF, F1b + HALF, nullptr, wv_n2g, wv_n2b, SFb + HALF, SLN + HALF, cm_n1g, cm_n1b);

    // ================= cross phase (fully merged; shared cm weights) =================
    float* outF = (float*)d_out;   // 2M rows fp32, [x-result; y-result] contiguous

    gemm(SLN, cm_kv_t, cm_kv_t, cm_kv_b, cm_kv_b, KVA, 1024, M2);       // KV once, both modalities
    gemm(SLN, cm_q_t,  cm_q_t,  cm_q_b,  cm_q_b,  XN,  512,  M2);       // Q all
    attn_cross_kernel<<<attnGrid2, 256, 0, stream>>>(XN, KVA, O, 0);
    gemm(O, cm_proj_t, cm_proj_t, cm_proj_b, cm_proj_b, XN, 512, M2);
    resln_kernel<1,1><<<rlGrid2, 256, 0, stream>>>(XN, SFb, nullptr, cm_n2g, cm_n2b, F1b, CN, cm_n1g, cm_n1b);

    gemm(CN, cm_q_t, cm_q_t, cm_q_b, cm_q_b, XN, 512, M2);
    attn_cross_kernel<<<attnGrid2, 256, 0, stream>>>(XN, KVA, O, 1);
    gemm(O, cm_proj_t, cm_proj_t, cm_proj_b, cm_proj_b, XN, 512, M2);
    resln_kernel<1,0><<<rlGrid2, 256, 0, stream>>>(XN, F1b, SFb, cm_n2g, cm_n2b, outF, nullptr, nullptr, nullptr);
}